// Round 10
// baseline (180.793 us; speedup 1.0000x reference)
//
#include <hip/hip_runtime.h>
#include <hip/hip_fp16.h>
#include <math.h>

#define NPROJ 96
#define NANG  96
#define DET   192
#define NPIX  16384            // 128*128
#define SLICE (NANG*DET)       // 18432 elements per projection
#define NROWS (NPROJ*NANG)     // 9216 sinogram rows total

// wq stores quad rows [16,112) only (reads touch rows 19..111)
#define WQROW0   16
#define WQROWS   96
#define WQSLICEB (WQROWS*128*16)   // 196608 bytes per projection

// DSD/DU = DSD/DV = 1000/3.5
#define KPROJ 285.7142857142857f

__device__ __forceinline__ float frcp(float x) { return __builtin_amdgcn_rcpf(x); }

__device__ __forceinline__ float ffract(float x) {
#if __has_builtin(__builtin_amdgcn_fractf)
    return __builtin_amdgcn_fractf(x);
#else
    return x - floorf(x);
#endif
}

typedef __fp16 h2 __attribute__((ext_vector_type(2)));

__device__ __forceinline__ unsigned pack2(float a, float b) {
    h2 p = __builtin_amdgcn_cvt_pkrtz(a, b);
    return __builtin_bit_cast(unsigned, p);
}
__device__ __forceinline__ h2 as_h2(unsigned u) { return __builtin_bit_cast(h2, u); }

#if __has_builtin(__builtin_amdgcn_fdot2)
#define FDOT2(a, b, c) __builtin_amdgcn_fdot2((a), (b), (c), false)
#else
__device__ __forceinline__ float FDOT2(h2 a, h2 b, float c) {
    return c + (float)a[0] * (float)b[0] + (float)a[1] * (float)b[1];
}
#endif

// ---------------------------------------------------------------------------
// K1: deriv = grad_lastdim(sino * weight) -> DIFFERENCE pairs, lean form:
// 576 blocks x 16 rows (NROWS/16 — r9 bug was SLICE/16 = 2x OOB): stage 16
// rows of sino*wgt in LDS (coalesced), one barrier, grad pairs, store.
// derivp[row][d] = half2(g[d], g[d+1]-g[d])  =>  lerp weight is (1, f).
// ---------------------------------------------------------------------------
__global__ __launch_bounds__(256) void k_deriv16(const float* __restrict__ sino,
                                                 const float* __restrict__ wgt,
                                                 unsigned* __restrict__ derivp) {
    __shared__ float sw[16 * DET];             // 12 KB
    const int tid   = threadIdx.x;
    const int base0 = blockIdx.x * (16 * DET);

    #pragma unroll
    for (int k = 0; k < 12; ++k) {
        const int i = k * 256 + tid;
        sw[i] = sino[base0 + i] * wgt[base0 + i];
    }
    __syncthreads();

    #pragma unroll
    for (int k = 0; k < 12; ++k) {
        const int i = k * 256 + tid;
        const int r = i / DET;                 // compiler magic-div
        const int d = i - r * DET;
        const float* row = sw + r * DET;
        auto grad = [&](int q) -> float {
            if (q == 0)        return row[1] - row[0];
            if (q >= DET - 1)  return row[DET-1] - row[DET-2];
            return 0.5f * (row[q+1] - row[q-1]);
        };
        const float g0 = grad(d), g1 = grad(d + 1);
        derivp[base0 + i] = pack2(g0, g1 - g0);
    }
}

// ---------------------------------------------------------------------------
// K2: 2D backprojection + cosine weighting — 4-way p-SHARE.
// Key fact: the A2D angle grid is the SAME for all 96 projections, so
// pos/i0/f per (pixel, angle) are p-independent. Old K2 recomputed them
// once per p (96x). Now each thread owns ONE pixel x FOUR consecutive p:
// per angle: one setup (2 fma, cvt, fract, pack, idx) + 4 gathers sharing
// one voffset against 4 block-uniform SGPR bases (p0 = blockIdx.y*4 —
// provably uniform, no r3 waterfall) + 4 FDOT2.
// Issue: ~11 -> ~4.25 slots/update; memory stream IDENTICAL to r8 (same
// addresses, same wave-gather count/lines); per-(px,p) summation order
// unchanged -> bit-identical output.
// grid (64 tiles of 256 px, 24 p-chunks) = 1536 blocks = 24 waves/CU.
// Epilogue per thread: 4 p x {quad scatter + tbl entry} — same totals.
// ---------------------------------------------------------------------------
__global__ __launch_bounds__(256) void k_bp2d_p4(const unsigned* __restrict__ derivp,
                                                 unsigned* __restrict__ wq_dw,
                                                 uint2* __restrict__ tbl) {
    __shared__ float sc[NANG], ss[NANG];
    __shared__ float sc3[4], ss3[4];
    __shared__ float buf[4][257];              // +1 pad: tid+1 read safe
    const int tid = threadIdx.x;
    const int p0  = blockIdx.y << 2;           // 4-share chunk (uniform)
    const int pix = (blockIdx.x << 8) + tid;   // 256-px tile = 2 rows
    const int u   = pix & 127;
    const int v   = pix >> 7;

    if (tid < NANG) {
        float s_, c_;
        sincosf((float)tid * (float)(3.14159265358979323846 / 96.0), &s_, &c_);
        sc[tid] = c_; ss[tid] = s_;
    }
    if (tid < 4) {
        float s_, c_;
        sincosf((float)(p0 + tid) * (float)(2.0 * 3.14159265358979323846 / 96.0), &s_, &c_);
        sc3[tid] = c_; ss3[tid] = s_;
    }

    const float fx = (float)u - 63.5f;
    const float fy = (float)v - 63.5f;

    float acc[4];
    #pragma unroll
    for (int j = 0; j < 4; ++j) acc[j] = 0.0f;

    __syncthreads();   // trig ready

    const unsigned* b0 = derivp + (p0 + 0) * SLICE;
    const unsigned* b1 = derivp + (p0 + 1) * SLICE;
    const unsigned* b2 = derivp + (p0 + 2) * SLICE;
    const unsigned* b3 = derivp + (p0 + 3) * SLICE;

    int aoff = 0;
    #pragma unroll 2
    for (int a = 0; a < NANG; ++a, aoff += DET) {
        const float cb = sc[a], sb = ss[a];
        const float pos = fmaf(cb, fx, fmaf(sb, fy, 95.5f));
        const int   i0  = (int)pos;            // pos in [5,186]
        const float f   = ffract(pos);
        const h2    wv  = as_h2(pack2(1.0f, f));
        const int   idx = aoff + i0;
        acc[0] = FDOT2(as_h2(b0[idx]), wv, acc[0]);
        acc[1] = FDOT2(as_h2(b1[idx]), wv, acc[1]);
        acc[2] = FDOT2(as_h2(b2[idx]), wv, acc[2]);
        acc[3] = FDOT2(as_h2(b3[idx]), wv, acc[3]);
    }

    const float w = 1000.0f * rsqrtf(1000000.0f + fx*fx + fy*fy);
    #pragma unroll
    for (int j = 0; j < 4; ++j) {
        acc[j] *= w;
        buf[j][tid] = acc[j];
    }
    __syncthreads();

    #pragma unroll
    for (int j = 0; j < 4; ++j) {
        const float v0 = acc[j];
        const float v1 = (u < 127) ? buf[j][tid + 1] : 0.0f;   // u=127 unused
        const unsigned pr = pack2(v0, v1 - v0);
        unsigned* sq = wq_dw + (p0 + j) * (WQROWS * 128 * 4);
        #pragma unroll
        for (int k = 0; k < 4; ++k) {
            const int vb = v - k;
            if (vb >= WQROW0 && vb < WQROW0 + WQROWS)
                sq[(((vb - WQROW0) << 7) + u) << 2 | k] = pr;
        }
        // K3 prologue table entry for (p0+j, pix)
        const float cb3  = sc3[j], sb3 = ss3[j];
        const float t3   = fmaf(fx, cb3,  fy * sb3);
        const float sd3  = fmaf(fy, cb3, -fx * sb3);
        const float invr = frcp(500.0f + t3);
        const float pu   = fmaf(KPROJ * sd3, invr, 63.5f);
        const int   iu0  = (int)pu;              // [11,116]
        const float fu   = ffract(pu);
        float w2 = 1000.0f * invr; w2 *= w2;
        const float Kz   = KPROJ * invr;         // > 0
        const unsigned kzi = (__builtin_bit_cast(unsigned, Kz) & ~127u) | (unsigned)iu0;
        uint2 e; e.x = pack2(w2, fu * w2); e.y = kzi;
        tbl[(p0 + j) * NPIX + pix] = e;          // coalesced dwordx2
    }
}

// ---------------------------------------------------------------------------
// K3: 3D cone-beam backprojection + PReLU — r8 version VERBATIM (88.7 us):
// 32-bit SADDR addressing + 1-beta-ahead quad issue + 2-ahead table
// prefetch. grid (64 y-pairs, 32 z-chunks) = 2048 blocks = 32 waves/CU.
// pu in [11,116], pv in [19,108] -> no masks.
// ---------------------------------------------------------------------------
struct QS {
    uint4    q0, q1;           // quad rows ivA..ivA+3 for z-pairs 0,1
    unsigned wuw;              // (w2, fu*w2) packed fp16
    float    fvA0, fvB0, fvA1, fvB1;
    int      d0, d1;           // ivB - ivA (0 or 1)
};

__global__ __launch_bounds__(256, 8) void k_bp3d_t2(const unsigned char* __restrict__ wq,
                                                    const unsigned char* __restrict__ tbl8,
                                                    const float* __restrict__ prelu,
                                                    float* __restrict__ out) {
    const int tid = threadIdx.x;
    const int x   = tid & 127;
    const int y   = (blockIdx.x << 1) | (tid >> 7);
    const int z0  = blockIdx.y << 2;
    const int pix = (y << 7) + x;

    const float zlo = (float)z0 - 63.5f;

    float acc[4];
    #pragma unroll
    for (int j = 0; j < 4; ++j) acc[j] = 0.0f;

    const unsigned pixoff = ((unsigned)pix) << 3;      // tbl byte offset

    auto TLOAD = [&](int b) -> uint2 {
        return *(const uint2*)(tbl8 + (pixoff + (unsigned)b * (NPIX * 8u)));
    };

    auto ISSUE = [&](QS& S, uint2 T, int b) {
        S.wuw = T.x;
        const int   iu0 = (int)(T.y & 127u);
        const float Kz  = __builtin_bit_cast(float, T.y & ~127u);
        const unsigned sbase = (unsigned)b * (unsigned)WQSLICEB
                             + (unsigned)(iu0 << 4) - (unsigned)(WQROW0 << 11);

        const float pvA0 = fmaf(Kz, zlo, 63.5f);
        const float pvB0 = pvA0 + Kz;
        const int   ivA0 = (int)pvA0;            // [19,108]
        S.d0   = (int)pvB0 - ivA0;               // 0 or 1
        S.fvA0 = ffract(pvA0);
        S.fvB0 = ffract(pvB0);
        S.q0   = *(const uint4*)(wq + (sbase + ((unsigned)ivA0 << 11)));

        const float pvA1 = fmaf(Kz, zlo + 2.0f, 63.5f);
        const float pvB1 = pvA1 + Kz;
        const int   ivA1 = (int)pvA1;
        S.d1   = (int)pvB1 - ivA1;
        S.fvA1 = ffract(pvA1);
        S.fvB1 = ffract(pvB1);
        S.q1   = *(const uint4*)(wq + (sbase + ((unsigned)ivA1 << 11)));
    };

    auto MATH = [&](const QS& S) {
        const h2 wuw = as_h2(S.wuw);
        {
            const float tA = FDOT2(as_h2(S.q0.x), wuw, 0.0f);
            const float bA = FDOT2(as_h2(S.q0.y), wuw, 0.0f);
            acc[0] += fmaf(S.fvA0, bA - tA, tA);
            const unsigned tBv = S.d0 ? S.q0.y : S.q0.x;
            const unsigned bBv = S.d0 ? S.q0.z : S.q0.y;
            const float tB = FDOT2(as_h2(tBv), wuw, 0.0f);
            const float bB = FDOT2(as_h2(bBv), wuw, 0.0f);
            acc[1] += fmaf(S.fvB0, bB - tB, tB);
        }
        {
            const float tA = FDOT2(as_h2(S.q1.x), wuw, 0.0f);
            const float bA = FDOT2(as_h2(S.q1.y), wuw, 0.0f);
            acc[2] += fmaf(S.fvA1, bA - tA, tA);
            const unsigned tBv = S.d1 ? S.q1.y : S.q1.x;
            const unsigned bBv = S.d1 ? S.q1.z : S.q1.y;
            const float tB = FDOT2(as_h2(tBv), wuw, 0.0f);
            const float bB = FDOT2(as_h2(bBv), wuw, 0.0f);
            acc[3] += fmaf(S.fvB1, bB - tB, tB);
        }
    };

    QS qa, qb;
    uint2 Ta = TLOAD(0);
    uint2 Tb = TLOAD(1);
    ISSUE(qa, Ta, 0);
    for (int b = 0; b < 94; b += 2) {
        Ta = TLOAD(b + 2);          // 2-ahead table prefetch
        ISSUE(qb, Tb, b + 1);       // 1-ahead quad issue
        MATH(qa);                   // consume quads issued last half-iter
        Tb = TLOAD(b + 3);          // max index 95 — no overrun
        ISSUE(qa, Ta, b + 2);
        MATH(qb);
    }
    ISSUE(qb, Tb, 95);
    MATH(qa);                       // beta 94
    MATH(qb);                       // beta 95

    const float a = prelu[0];
    #pragma unroll
    for (int j = 0; j < 4; ++j) {
        const float v = acc[j];
        out[((z0 + j) << 14) + (y << 7) + x] = (v >= 0.0f) ? v : a * v;
    }
}

// ---------------------------------------------------------------------------
extern "C" void kernel_launch(void* const* d_in, const int* in_sizes, int n_in,
                              void* d_out, int out_size, void* d_ws, size_t ws_size,
                              hipStream_t stream) {
    const float* sino  = (const float*)d_in[0];   // (1,1,96,96,192)
    const float* wgt   = (const float*)d_in[1];   // (1,96,96,192)
    const float* prelu = (const float*)d_in[2];   // (1,)
    float* out = (float*)d_out;                   // 128^3 floats

    unsigned char* wsb = (unsigned char*)d_ws;
    unsigned* wq_dw  = (unsigned*)wsb;                                   // 18.87 MB quads (rows 16..111)
    uint2*    tbl    = (uint2*)(wsb + (size_t)NPROJ * WQSLICEB);         // 12.58 MB table
    unsigned* derivp = (unsigned*)(wsb + (size_t)NPROJ * WQSLICEB
                                       + (size_t)NPROJ * NPIX * 8);      // 7.08 MB pairs

    k_deriv16<<<dim3(NROWS / 16),  dim3(256), 0, stream>>>(sino, wgt, derivp);   // 576 blocks (16 ROWS each)
    k_bp2d_p4<<<dim3(64, 24),      dim3(256), 0, stream>>>(derivp, wq_dw, tbl);
    k_bp3d_t2<<<dim3(64, 32),      dim3(256), 0, stream>>>((const unsigned char*)wq_dw,
                                                           (const unsigned char*)tbl, prelu, out);
}

// Round 11
// 179.463 us; speedup vs baseline: 1.0074x; 1.0074x over previous
//
#include <hip/hip_runtime.h>
#include <hip/hip_fp16.h>
#include <math.h>

#define NPROJ 96
#define NANG  96
#define DET   192
#define NPIX  16384            // 128*128
#define SLICE (NANG*DET)       // 18432 elements per projection
#define NROWS (NPROJ*NANG)     // 9216 sinogram rows total

// wq stores quad rows [16,112) only (reads touch rows 19..111)
#define WQROW0   16
#define WQROWS   96
#define WQSLICEB (WQROWS*128*16)   // 196608 bytes per projection

// DSD/DU = DSD/DV = 1000/3.5
#define KPROJ 285.7142857142857f

__device__ __forceinline__ float frcp(float x) { return __builtin_amdgcn_rcpf(x); }

__device__ __forceinline__ float ffract(float x) {
#if __has_builtin(__builtin_amdgcn_fractf)
    return __builtin_amdgcn_fractf(x);
#else
    return x - floorf(x);
#endif
}

typedef __fp16 h2 __attribute__((ext_vector_type(2)));

__device__ __forceinline__ unsigned pack2(float a, float b) {
    h2 p = __builtin_amdgcn_cvt_pkrtz(a, b);
    return __builtin_bit_cast(unsigned, p);
}
__device__ __forceinline__ h2 as_h2(unsigned u) { return __builtin_bit_cast(h2, u); }

#if __has_builtin(__builtin_amdgcn_fdot2)
#define FDOT2(a, b, c) __builtin_amdgcn_fdot2((a), (b), (c), false)
#else
__device__ __forceinline__ float FDOT2(h2 a, h2 b, float c) {
    return c + (float)a[0] * (float)b[0] + (float)a[1] * (float)b[1];
}
#endif

// ---------------------------------------------------------------------------
// K1: deriv = grad_lastdim(sino * weight) -> DIFFERENCE pairs, lean form:
// 576 blocks x 16 rows: stage 16 rows of sino*wgt in LDS (coalesced), one
// barrier, grad pairs, store. derivp[row][d] = half2(g[d], g[d+1]-g[d]).
// ---------------------------------------------------------------------------
__global__ __launch_bounds__(256) void k_deriv16(const float* __restrict__ sino,
                                                 const float* __restrict__ wgt,
                                                 unsigned* __restrict__ derivp) {
    __shared__ float sw[16 * DET];             // 12 KB
    const int tid   = threadIdx.x;
    const int base0 = blockIdx.x * (16 * DET);

    #pragma unroll
    for (int k = 0; k < 12; ++k) {
        const int i = k * 256 + tid;
        sw[i] = sino[base0 + i] * wgt[base0 + i];
    }
    __syncthreads();

    #pragma unroll
    for (int k = 0; k < 12; ++k) {
        const int i = k * 256 + tid;
        const int r = i / DET;                 // compiler magic-div
        const int d = i - r * DET;
        const float* row = sw + r * DET;
        auto grad = [&](int q) -> float {
            if (q == 0)        return row[1] - row[0];
            if (q >= DET - 1)  return row[DET-1] - row[DET-2];
            return 0.5f * (row[q+1] - row[q-1]);
        };
        const float g0 = grad(d), g1 = grad(d + 1);
        derivp[base0 + i] = pack2(g0, g1 - g0);
    }
}

// ---------------------------------------------------------------------------
// K2: 2D backprojection + cosine weighting — 4-way p-share + EXPLICIT
// PIPELINE (the r8 K3 schedule, ported):
//   TRIG(a+2) 2-ahead into registers  (kills per-iter lgkmcnt serial wait)
//   ISSUE(a+1) 1-ahead: pos/idx + fire 4 gathers into ping-pong struct
//   MATH(a): 4 FDOT2 on values issued a full iteration ago
// Same gather stream, same math order as r10 -> bit-identical output; only
// the schedule changes. This is the Theory-A test: if K2 was
// latency-serialized, this recovers 15-25 us; if the gather machine is the
// floor (Theory B), it is neutral and next step is K1-fusion / roofline.
// grid (64 tiles of 256 px, 24 p-chunks) = 1536 blocks = 24 waves/CU.
// ---------------------------------------------------------------------------
__global__ __launch_bounds__(256) void k_bp2d_p4s(const unsigned* __restrict__ derivp,
                                                  unsigned* __restrict__ wq_dw,
                                                  uint2* __restrict__ tbl) {
    __shared__ float sc[NANG], ss[NANG];
    __shared__ float sc3[4], ss3[4];
    __shared__ float buf[4][257];              // +1 pad: tid+1 read safe
    const int tid = threadIdx.x;
    const int p0  = blockIdx.y << 2;           // 4-share chunk (uniform)
    const int pix = (blockIdx.x << 8) + tid;   // 256-px tile = 2 rows
    const int u   = pix & 127;
    const int v   = pix >> 7;

    if (tid < NANG) {
        float s_, c_;
        sincosf((float)tid * (float)(3.14159265358979323846 / 96.0), &s_, &c_);
        sc[tid] = c_; ss[tid] = s_;
    }
    if (tid < 4) {
        float s_, c_;
        sincosf((float)(p0 + tid) * (float)(2.0 * 3.14159265358979323846 / 96.0), &s_, &c_);
        sc3[tid] = c_; ss3[tid] = s_;
    }

    const float fx = (float)u - 63.5f;
    const float fy = (float)v - 63.5f;

    float acc[4];
    #pragma unroll
    for (int j = 0; j < 4; ++j) acc[j] = 0.0f;

    __syncthreads();   // trig ready

    const unsigned* b0 = derivp + (p0 + 0) * SLICE;
    const unsigned* b1 = derivp + (p0 + 1) * SLICE;
    const unsigned* b2 = derivp + (p0 + 2) * SLICE;
    const unsigned* b3 = derivp + (p0 + 3) * SLICE;

    struct G { unsigned q0, q1, q2, q3, wv; };

    auto TRIG = [&](int a) -> float2 {
        return make_float2(sc[a], ss[a]);       // LDS reads, 2-ahead
    };
    auto ISSUE = [&](G& S, float2 T, int a) {
        const float pos = fmaf(T.x, fx, fmaf(T.y, fy, 95.5f));
        const int   i0  = (int)pos;            // pos in [5,186]
        const float f   = ffract(pos);
        S.wv = pack2(1.0f, f);
        const int idx = a * DET + i0;
        S.q0 = b0[idx]; S.q1 = b1[idx]; S.q2 = b2[idx]; S.q3 = b3[idx];
    };
    auto MATH = [&](const G& S) {
        const h2 wv = as_h2(S.wv);
        acc[0] = FDOT2(as_h2(S.q0), wv, acc[0]);
        acc[1] = FDOT2(as_h2(S.q1), wv, acc[1]);
        acc[2] = FDOT2(as_h2(S.q2), wv, acc[2]);
        acc[3] = FDOT2(as_h2(S.q3), wv, acc[3]);
    };

    G ga, gb;
    float2 Ta = TRIG(0);
    float2 Tb = TRIG(1);
    ISSUE(ga, Ta, 0);
    for (int a = 0; a < 94; a += 2) {
        Ta = TRIG(a + 2);           // 2-ahead trig prefetch
        ISSUE(gb, Tb, a + 1);       // 1-ahead gather issue
        MATH(ga);                   // consume gathers issued last half-iter
        Tb = TRIG(a + 3);           // max index 95 — no overrun
        ISSUE(ga, Ta, a + 2);
        MATH(gb);
    }
    ISSUE(gb, Tb, 95);
    MATH(ga);                       // angle 94
    MATH(gb);                       // angle 95

    const float w = 1000.0f * rsqrtf(1000000.0f + fx*fx + fy*fy);
    #pragma unroll
    for (int j = 0; j < 4; ++j) {
        acc[j] *= w;
        buf[j][tid] = acc[j];
    }
    __syncthreads();

    #pragma unroll
    for (int j = 0; j < 4; ++j) {
        const float v0 = acc[j];
        const float v1 = (u < 127) ? buf[j][tid + 1] : 0.0f;   // u=127 unused
        const unsigned pr = pack2(v0, v1 - v0);
        unsigned* sq = wq_dw + (p0 + j) * (WQROWS * 128 * 4);
        #pragma unroll
        for (int k = 0; k < 4; ++k) {
            const int vb = v - k;
            if (vb >= WQROW0 && vb < WQROW0 + WQROWS)
                sq[(((vb - WQROW0) << 7) + u) << 2 | k] = pr;
        }
        // K3 prologue table entry for (p0+j, pix)
        const float cb3  = sc3[j], sb3 = ss3[j];
        const float t3   = fmaf(fx, cb3,  fy * sb3);
        const float sd3  = fmaf(fy, cb3, -fx * sb3);
        const float invr = frcp(500.0f + t3);
        const float pu   = fmaf(KPROJ * sd3, invr, 63.5f);
        const int   iu0  = (int)pu;              // [11,116]
        const float fu   = ffract(pu);
        float w2 = 1000.0f * invr; w2 *= w2;
        const float Kz   = KPROJ * invr;         // > 0
        const unsigned kzi = (__builtin_bit_cast(unsigned, Kz) & ~127u) | (unsigned)iu0;
        uint2 e; e.x = pack2(w2, fu * w2); e.y = kzi;
        tbl[(p0 + j) * NPIX + pix] = e;          // coalesced dwordx2
    }
}

// ---------------------------------------------------------------------------
// K3: 3D cone-beam backprojection + PReLU — r8 version VERBATIM (~89-91 us):
// 32-bit SADDR addressing + 1-beta-ahead quad issue + 2-ahead table
// prefetch. grid (64 y-pairs, 32 z-chunks) = 2048 blocks = 32 waves/CU.
// pu in [11,116], pv in [19,108] -> no masks.
// ---------------------------------------------------------------------------
struct QS {
    uint4    q0, q1;           // quad rows ivA..ivA+3 for z-pairs 0,1
    unsigned wuw;              // (w2, fu*w2) packed fp16
    float    fvA0, fvB0, fvA1, fvB1;
    int      d0, d1;           // ivB - ivA (0 or 1)
};

__global__ __launch_bounds__(256, 8) void k_bp3d_t2(const unsigned char* __restrict__ wq,
                                                    const unsigned char* __restrict__ tbl8,
                                                    const float* __restrict__ prelu,
                                                    float* __restrict__ out) {
    const int tid = threadIdx.x;
    const int x   = tid & 127;
    const int y   = (blockIdx.x << 1) | (tid >> 7);
    const int z0  = blockIdx.y << 2;
    const int pix = (y << 7) + x;

    const float zlo = (float)z0 - 63.5f;

    float acc[4];
    #pragma unroll
    for (int j = 0; j < 4; ++j) acc[j] = 0.0f;

    const unsigned pixoff = ((unsigned)pix) << 3;      // tbl byte offset

    auto TLOAD = [&](int b) -> uint2 {
        return *(const uint2*)(tbl8 + (pixoff + (unsigned)b * (NPIX * 8u)));
    };

    auto ISSUE = [&](QS& S, uint2 T, int b) {
        S.wuw = T.x;
        const int   iu0 = (int)(T.y & 127u);
        const float Kz  = __builtin_bit_cast(float, T.y & ~127u);
        const unsigned sbase = (unsigned)b * (unsigned)WQSLICEB
                             + (unsigned)(iu0 << 4) - (unsigned)(WQROW0 << 11);

        const float pvA0 = fmaf(Kz, zlo, 63.5f);
        const float pvB0 = pvA0 + Kz;
        const int   ivA0 = (int)pvA0;            // [19,108]
        S.d0   = (int)pvB0 - ivA0;               // 0 or 1
        S.fvA0 = ffract(pvA0);
        S.fvB0 = ffract(pvB0);
        S.q0   = *(const uint4*)(wq + (sbase + ((unsigned)ivA0 << 11)));

        const float pvA1 = fmaf(Kz, zlo + 2.0f, 63.5f);
        const float pvB1 = pvA1 + Kz;
        const int   ivA1 = (int)pvA1;
        S.d1   = (int)pvB1 - ivA1;
        S.fvA1 = ffract(pvA1);
        S.fvB1 = ffract(pvB1);
        S.q1   = *(const uint4*)(wq + (sbase + ((unsigned)ivA1 << 11)));
    };

    auto MATH = [&](const QS& S) {
        const h2 wuw = as_h2(S.wuw);
        {
            const float tA = FDOT2(as_h2(S.q0.x), wuw, 0.0f);
            const float bA = FDOT2(as_h2(S.q0.y), wuw, 0.0f);
            acc[0] += fmaf(S.fvA0, bA - tA, tA);
            const unsigned tBv = S.d0 ? S.q0.y : S.q0.x;
            const unsigned bBv = S.d0 ? S.q0.z : S.q0.y;
            const float tB = FDOT2(as_h2(tBv), wuw, 0.0f);
            const float bB = FDOT2(as_h2(bBv), wuw, 0.0f);
            acc[1] += fmaf(S.fvB0, bB - tB, tB);
        }
        {
            const float tA = FDOT2(as_h2(S.q1.x), wuw, 0.0f);
            const float bA = FDOT2(as_h2(S.q1.y), wuw, 0.0f);
            acc[2] += fmaf(S.fvA1, bA - tA, tA);
            const unsigned tBv = S.d1 ? S.q1.y : S.q1.x;
            const unsigned bBv = S.d1 ? S.q1.z : S.q1.y;
            const float tB = FDOT2(as_h2(tBv), wuw, 0.0f);
            const float bB = FDOT2(as_h2(bBv), wuw, 0.0f);
            acc[3] += fmaf(S.fvB1, bB - tB, tB);
        }
    };

    QS qa, qb;
    uint2 Ta = TLOAD(0);
    uint2 Tb = TLOAD(1);
    ISSUE(qa, Ta, 0);
    for (int b = 0; b < 94; b += 2) {
        Ta = TLOAD(b + 2);          // 2-ahead table prefetch
        ISSUE(qb, Tb, b + 1);       // 1-ahead quad issue
        MATH(qa);                   // consume quads issued last half-iter
        Tb = TLOAD(b + 3);          // max index 95 — no overrun
        ISSUE(qa, Ta, b + 2);
        MATH(qb);
    }
    ISSUE(qb, Tb, 95);
    MATH(qa);                       // beta 94
    MATH(qb);                       // beta 95

    const float a = prelu[0];
    #pragma unroll
    for (int j = 0; j < 4; ++j) {
        const float v = acc[j];
        out[((z0 + j) << 14) + (y << 7) + x] = (v >= 0.0f) ? v : a * v;
    }
}

// ---------------------------------------------------------------------------
extern "C" void kernel_launch(void* const* d_in, const int* in_sizes, int n_in,
                              void* d_out, int out_size, void* d_ws, size_t ws_size,
                              hipStream_t stream) {
    const float* sino  = (const float*)d_in[0];   // (1,1,96,96,192)
    const float* wgt   = (const float*)d_in[1];   // (1,96,96,192)
    const float* prelu = (const float*)d_in[2];   // (1,)
    float* out = (float*)d_out;                   // 128^3 floats

    unsigned char* wsb = (unsigned char*)d_ws;
    unsigned* wq_dw  = (unsigned*)wsb;                                   // 18.87 MB quads (rows 16..111)
    uint2*    tbl    = (uint2*)(wsb + (size_t)NPROJ * WQSLICEB);         // 12.58 MB table
    unsigned* derivp = (unsigned*)(wsb + (size_t)NPROJ * WQSLICEB
                                       + (size_t)NPROJ * NPIX * 8);      // 7.08 MB pairs

    k_deriv16 <<<dim3(NROWS / 16), dim3(256), 0, stream>>>(sino, wgt, derivp);   // 576 blocks (16 ROWS each)
    k_bp2d_p4s<<<dim3(64, 24),     dim3(256), 0, stream>>>(derivp, wq_dw, tbl);
    k_bp3d_t2 <<<dim3(64, 32),     dim3(256), 0, stream>>>((const unsigned char*)wq_dw,
                                                           (const unsigned char*)tbl, prelu, out);
}

// Round 12
// 174.784 us; speedup vs baseline: 1.0344x; 1.0268x over previous
//
#include <hip/hip_runtime.h>
#include <hip/hip_fp16.h>
#include <math.h>

#define NPROJ 96
#define NANG  96
#define DET   192
#define NPIX  16384            // 128*128
#define SLICE (NANG*DET)       // 18432 elements per projection
#define NROWS (NPROJ*NANG)     // 9216 sinogram rows total

// wq stores quad rows [16,112) only (reads touch rows 19..111)
#define WQROW0   16
#define WQROWS   96
#define WQSLICEB (WQROWS*128*16)   // 196608 bytes per projection

// DSD/DU = DSD/DV = 1000/3.5
#define KPROJ 285.7142857142857f

__device__ __forceinline__ float frcp(float x) { return __builtin_amdgcn_rcpf(x); }

__device__ __forceinline__ float ffract(float x) {
#if __has_builtin(__builtin_amdgcn_fractf)
    return __builtin_amdgcn_fractf(x);
#else
    return x - floorf(x);
#endif
}

typedef __fp16 h2 __attribute__((ext_vector_type(2)));

__device__ __forceinline__ unsigned pack2(float a, float b) {
    h2 p = __builtin_amdgcn_cvt_pkrtz(a, b);
    return __builtin_bit_cast(unsigned, p);
}
__device__ __forceinline__ h2 as_h2(unsigned u) { return __builtin_bit_cast(h2, u); }

#if __has_builtin(__builtin_amdgcn_fdot2)
#define FDOT2(a, b, c) __builtin_amdgcn_fdot2((a), (b), (c), false)
#else
__device__ __forceinline__ float FDOT2(h2 a, h2 b, float c) {
    return c + (float)a[0] * (float)b[0] + (float)a[1] * (float)b[1];
}
#endif

// ---------------------------------------------------------------------------
// K1: deriv pairs in p4-INTERLEAVED layout:
//   dp4[pc][a*DET + d] = uint4{ pair(4pc+0,a,d), .., pair(4pc+3,a,d) }
//   pair(p,a,d) = half2(g[d], g[d+1]-g[d]) of row (p,a) of sino*wgt.
// Purpose: K2's 4 same-idx dword gathers (4 slices) become ONE dwordx4
// gather — 4x fewer wave-gathers in the TA-bound K2 loop (r11 finding).
// Block = 192 thr (one per d), 4 rows of one angle staged in LDS; uint4
// stores are consecutive-d = consecutive 16B -> fully coalesced.
// grid (96 a, 24 pc) = 2304 blocks.
// ---------------------------------------------------------------------------
__global__ __launch_bounds__(192) void k_deriv4(const float* __restrict__ sino,
                                                const float* __restrict__ wgt,
                                                uint4* __restrict__ dp4) {
    __shared__ float sw[4][DET];               // 3 KB
    const int d  = threadIdx.x;                // 0..191
    const int a  = blockIdx.x;                 // angle
    const int pc = blockIdx.y;                 // p-chunk (4 slices)

    #pragma unroll
    for (int j = 0; j < 4; ++j) {
        const int r = (4*pc + j) * NANG + a;   // sinogram row (p, a)
        sw[j][d] = sino[r*DET + d] * wgt[r*DET + d];
    }
    __syncthreads();

    unsigned pr[4];
    #pragma unroll
    for (int j = 0; j < 4; ++j) {
        const float* row = sw[j];
        auto grad = [&](int q) -> float {
            if (q == 0)       return row[1] - row[0];
            if (q >= DET-1)   return row[DET-1] - row[DET-2];
            return 0.5f * (row[q+1] - row[q-1]);
        };
        const float g0 = grad(d), g1 = grad(d + 1);
        pr[j] = pack2(g0, g1 - g0);
    }
    uint4 q; q.x = pr[0]; q.y = pr[1]; q.z = pr[2]; q.w = pr[3];
    dp4[((size_t)pc * SLICE) + a * DET + d] = q;   // coalesced 16B stores
}

// ---------------------------------------------------------------------------
// K2: 2D backprojection + cosine weighting — 4-way p-share, ONE dwordx4
// gather per thread-angle (was 4 dword gathers). Same bytes, same values,
// same FDOT2 order as r11 -> bit-identical output; only the gather
// instruction count changes (2.36M -> 0.59M wave-gathers).
// Keeps the 1-ahead issue ping-pong (neutral cost). pc = blockIdx.y is the
// p-chunk, matching dp4's layout directly.
// grid (64 tiles of 256 px, 24 pc) = 1536 blocks = 24 waves/CU.
// Epilogue (quad scatter + tbl) unchanged.
// ---------------------------------------------------------------------------
__global__ __launch_bounds__(256) void k_bp2d_q4(const uint4* __restrict__ dp4,
                                                 unsigned* __restrict__ wq_dw,
                                                 uint2* __restrict__ tbl) {
    __shared__ float sc[NANG], ss[NANG];
    __shared__ float sc3[4], ss3[4];
    __shared__ float buf[4][257];              // +1 pad: tid+1 read safe
    const int tid = threadIdx.x;
    const int pc  = blockIdx.y;                // p-chunk
    const int p0  = pc << 2;
    const int pix = (blockIdx.x << 8) + tid;   // 256-px tile = 2 rows
    const int u   = pix & 127;
    const int v   = pix >> 7;

    if (tid < NANG) {
        float s_, c_;
        sincosf((float)tid * (float)(3.14159265358979323846 / 96.0), &s_, &c_);
        sc[tid] = c_; ss[tid] = s_;
    }
    if (tid < 4) {
        float s_, c_;
        sincosf((float)(p0 + tid) * (float)(2.0 * 3.14159265358979323846 / 96.0), &s_, &c_);
        sc3[tid] = c_; ss3[tid] = s_;
    }

    const float fx = (float)u - 63.5f;
    const float fy = (float)v - 63.5f;

    float acc[4];
    #pragma unroll
    for (int j = 0; j < 4; ++j) acc[j] = 0.0f;

    __syncthreads();   // trig ready

    const uint4* bq = dp4 + (size_t)pc * SLICE;

    struct G { uint4 q; unsigned wv; };

    auto TRIG = [&](int a) -> float2 {
        return make_float2(sc[a], ss[a]);
    };
    auto ISSUE = [&](G& S, float2 T, int a) {
        const float pos = fmaf(T.x, fx, fmaf(T.y, fy, 95.5f));
        const int   i0  = (int)pos;            // pos in [5,186]
        const float f   = ffract(pos);
        S.wv = pack2(1.0f, f);
        S.q  = bq[a * DET + i0];               // ONE dwordx4 gather
    };
    auto MATH = [&](const G& S) {
        const h2 wv = as_h2(S.wv);
        acc[0] = FDOT2(as_h2(S.q.x), wv, acc[0]);
        acc[1] = FDOT2(as_h2(S.q.y), wv, acc[1]);
        acc[2] = FDOT2(as_h2(S.q.z), wv, acc[2]);
        acc[3] = FDOT2(as_h2(S.q.w), wv, acc[3]);
    };

    G ga, gb;
    float2 Ta = TRIG(0);
    float2 Tb = TRIG(1);
    ISSUE(ga, Ta, 0);
    for (int a = 0; a < 94; a += 2) {
        Ta = TRIG(a + 2);           // 2-ahead trig prefetch
        ISSUE(gb, Tb, a + 1);       // 1-ahead gather issue
        MATH(ga);                   // consume gathers issued last half-iter
        Tb = TRIG(a + 3);           // max index 95 — no overrun
        ISSUE(ga, Ta, a + 2);
        MATH(gb);
    }
    ISSUE(gb, Tb, 95);
    MATH(ga);                       // angle 94
    MATH(gb);                       // angle 95

    const float w = 1000.0f * rsqrtf(1000000.0f + fx*fx + fy*fy);
    #pragma unroll
    for (int j = 0; j < 4; ++j) {
        acc[j] *= w;
        buf[j][tid] = acc[j];
    }
    __syncthreads();

    #pragma unroll
    for (int j = 0; j < 4; ++j) {
        const float v0 = acc[j];
        const float v1 = (u < 127) ? buf[j][tid + 1] : 0.0f;   // u=127 unused
        const unsigned pr = pack2(v0, v1 - v0);
        unsigned* sq = wq_dw + (p0 + j) * (WQROWS * 128 * 4);
        #pragma unroll
        for (int k = 0; k < 4; ++k) {
            const int vb = v - k;
            if (vb >= WQROW0 && vb < WQROW0 + WQROWS)
                sq[(((vb - WQROW0) << 7) + u) << 2 | k] = pr;
        }
        // K3 prologue table entry for (p0+j, pix)
        const float cb3  = sc3[j], sb3 = ss3[j];
        const float t3   = fmaf(fx, cb3,  fy * sb3);
        const float sd3  = fmaf(fy, cb3, -fx * sb3);
        const float invr = frcp(500.0f + t3);
        const float pu   = fmaf(KPROJ * sd3, invr, 63.5f);
        const int   iu0  = (int)pu;              // [11,116]
        const float fu   = ffract(pu);
        float w2 = 1000.0f * invr; w2 *= w2;
        const float Kz   = KPROJ * invr;         // > 0
        const unsigned kzi = (__builtin_bit_cast(unsigned, Kz) & ~127u) | (unsigned)iu0;
        uint2 e; e.x = pack2(w2, fu * w2); e.y = kzi;
        tbl[(p0 + j) * NPIX + pix] = e;          // coalesced dwordx2
    }
}

// ---------------------------------------------------------------------------
// K3: 3D cone-beam backprojection + PReLU — r8 version VERBATIM (~88.5 us):
// 32-bit SADDR addressing + 1-beta-ahead quad issue + 2-ahead table
// prefetch. grid (64 y-pairs, 32 z-chunks) = 2048 blocks = 32 waves/CU.
// pu in [11,116], pv in [19,108] -> no masks.
// ---------------------------------------------------------------------------
struct QS {
    uint4    q0, q1;           // quad rows ivA..ivA+3 for z-pairs 0,1
    unsigned wuw;              // (w2, fu*w2) packed fp16
    float    fvA0, fvB0, fvA1, fvB1;
    int      d0, d1;           // ivB - ivA (0 or 1)
};

__global__ __launch_bounds__(256, 8) void k_bp3d_t2(const unsigned char* __restrict__ wq,
                                                    const unsigned char* __restrict__ tbl8,
                                                    const float* __restrict__ prelu,
                                                    float* __restrict__ out) {
    const int tid = threadIdx.x;
    const int x   = tid & 127;
    const int y   = (blockIdx.x << 1) | (tid >> 7);
    const int z0  = blockIdx.y << 2;
    const int pix = (y << 7) + x;

    const float zlo = (float)z0 - 63.5f;

    float acc[4];
    #pragma unroll
    for (int j = 0; j < 4; ++j) acc[j] = 0.0f;

    const unsigned pixoff = ((unsigned)pix) << 3;      // tbl byte offset

    auto TLOAD = [&](int b) -> uint2 {
        return *(const uint2*)(tbl8 + (pixoff + (unsigned)b * (NPIX * 8u)));
    };

    auto ISSUE = [&](QS& S, uint2 T, int b) {
        S.wuw = T.x;
        const int   iu0 = (int)(T.y & 127u);
        const float Kz  = __builtin_bit_cast(float, T.y & ~127u);
        const unsigned sbase = (unsigned)b * (unsigned)WQSLICEB
                             + (unsigned)(iu0 << 4) - (unsigned)(WQROW0 << 11);

        const float pvA0 = fmaf(Kz, zlo, 63.5f);
        const float pvB0 = pvA0 + Kz;
        const int   ivA0 = (int)pvA0;            // [19,108]
        S.d0   = (int)pvB0 - ivA0;               // 0 or 1
        S.fvA0 = ffract(pvA0);
        S.fvB0 = ffract(pvB0);
        S.q0   = *(const uint4*)(wq + (sbase + ((unsigned)ivA0 << 11)));

        const float pvA1 = fmaf(Kz, zlo + 2.0f, 63.5f);
        const float pvB1 = pvA1 + Kz;
        const int   ivA1 = (int)pvA1;
        S.d1   = (int)pvB1 - ivA1;
        S.fvA1 = ffract(pvA1);
        S.fvB1 = ffract(pvB1);
        S.q1   = *(const uint4*)(wq + (sbase + ((unsigned)ivA1 << 11)));
    };

    auto MATH = [&](const QS& S) {
        const h2 wuw = as_h2(S.wuw);
        {
            const float tA = FDOT2(as_h2(S.q0.x), wuw, 0.0f);
            const float bA = FDOT2(as_h2(S.q0.y), wuw, 0.0f);
            acc[0] += fmaf(S.fvA0, bA - tA, tA);
            const unsigned tBv = S.d0 ? S.q0.y : S.q0.x;
            const unsigned bBv = S.d0 ? S.q0.z : S.q0.y;
            const float tB = FDOT2(as_h2(tBv), wuw, 0.0f);
            const float bB = FDOT2(as_h2(bBv), wuw, 0.0f);
            acc[1] += fmaf(S.fvB0, bB - tB, tB);
        }
        {
            const float tA = FDOT2(as_h2(S.q1.x), wuw, 0.0f);
            const float bA = FDOT2(as_h2(S.q1.y), wuw, 0.0f);
            acc[2] += fmaf(S.fvA1, bA - tA, tA);
            const unsigned tBv = S.d1 ? S.q1.y : S.q1.x;
            const unsigned bBv = S.d1 ? S.q1.z : S.q1.y;
            const float tB = FDOT2(as_h2(tBv), wuw, 0.0f);
            const float bB = FDOT2(as_h2(bBv), wuw, 0.0f);
            acc[3] += fmaf(S.fvB1, bB - tB, tB);
        }
    };

    QS qa, qb;
    uint2 Ta = TLOAD(0);
    uint2 Tb = TLOAD(1);
    ISSUE(qa, Ta, 0);
    for (int b = 0; b < 94; b += 2) {
        Ta = TLOAD(b + 2);          // 2-ahead table prefetch
        ISSUE(qb, Tb, b + 1);       // 1-ahead quad issue
        MATH(qa);                   // consume quads issued last half-iter
        Tb = TLOAD(b + 3);          // max index 95 — no overrun
        ISSUE(qa, Ta, b + 2);
        MATH(qb);
    }
    ISSUE(qb, Tb, 95);
    MATH(qa);                       // beta 94
    MATH(qb);                       // beta 95

    const float a = prelu[0];
    #pragma unroll
    for (int j = 0; j < 4; ++j) {
        const float v = acc[j];
        out[((z0 + j) << 14) + (y << 7) + x] = (v >= 0.0f) ? v : a * v;
    }
}

// ---------------------------------------------------------------------------
extern "C" void kernel_launch(void* const* d_in, const int* in_sizes, int n_in,
                              void* d_out, int out_size, void* d_ws, size_t ws_size,
                              hipStream_t stream) {
    const float* sino  = (const float*)d_in[0];   // (1,1,96,96,192)
    const float* wgt   = (const float*)d_in[1];   // (1,96,96,192)
    const float* prelu = (const float*)d_in[2];   // (1,)
    float* out = (float*)d_out;                   // 128^3 floats

    unsigned char* wsb = (unsigned char*)d_ws;
    unsigned* wq_dw  = (unsigned*)wsb;                                   // 18.87 MB quads (rows 16..111)
    uint2*    tbl    = (uint2*)(wsb + (size_t)NPROJ * WQSLICEB);         // 12.58 MB table
    uint4*    dp4    = (uint4*)(wsb + (size_t)NPROJ * WQSLICEB
                                     + (size_t)NPROJ * NPIX * 8);        // 7.08 MB p4-interleaved pairs

    k_deriv4 <<<dim3(NANG, NPROJ/4), dim3(192), 0, stream>>>(sino, wgt, dp4);   // 2304 blocks
    k_bp2d_q4<<<dim3(64, 24),        dim3(256), 0, stream>>>(dp4, wq_dw, tbl);
    k_bp3d_t2<<<dim3(64, 32),        dim3(256), 0, stream>>>((const unsigned char*)wq_dw,
                                                             (const unsigned char*)tbl, prelu, out);
}

// Round 13
// 174.167 us; speedup vs baseline: 1.0380x; 1.0035x over previous
//
#include <hip/hip_runtime.h>
#include <hip/hip_fp16.h>
#include <math.h>

#define NPROJ 96
#define NANG  96
#define DET   192
#define NPIX  16384            // 128*128
#define SLICE (NANG*DET)       // 18432 elements per projection
#define NROWS (NPROJ*NANG)     // 9216 sinogram rows total

// wq stores quad rows [16,112) only (reads touch rows 19..111)
#define WQROW0   16
#define WQROWS   96
#define WQSLICEB (WQROWS*128*16)   // 196608 bytes per projection

// DSD/DU = DSD/DV = 1000/3.5
#define KPROJ 285.7142857142857f

__device__ __forceinline__ float frcp(float x) { return __builtin_amdgcn_rcpf(x); }

__device__ __forceinline__ float ffract(float x) {
#if __has_builtin(__builtin_amdgcn_fractf)
    return __builtin_amdgcn_fractf(x);
#else
    return x - floorf(x);
#endif
}

typedef __fp16 h2 __attribute__((ext_vector_type(2)));

__device__ __forceinline__ unsigned pack2(float a, float b) {
    h2 p = __builtin_amdgcn_cvt_pkrtz(a, b);
    return __builtin_bit_cast(unsigned, p);
}
__device__ __forceinline__ h2 as_h2(unsigned u) { return __builtin_bit_cast(h2, u); }

#if __has_builtin(__builtin_amdgcn_fdot2)
#define FDOT2(a, b, c) __builtin_amdgcn_fdot2((a), (b), (c), false)
#else
__device__ __forceinline__ float FDOT2(h2 a, h2 b, float c) {
    return c + (float)a[0] * (float)b[0] + (float)a[1] * (float)b[1];
}
#endif

// ---------------------------------------------------------------------------
// K1: deriv pairs in p4-INTERLEAVED layout (r12 verbatim):
//   dp4[pc][a*DET + d] = uint4{ pair(4pc+0,a,d), .., pair(4pc+3,a,d) }
//   pair(p,a,d) = half2(g[d], g[d+1]-g[d]) of row (p,a) of sino*wgt.
// grid (96 a, 24 pc) = 2304 blocks; coalesced 16B stores.
// ---------------------------------------------------------------------------
__global__ __launch_bounds__(192) void k_deriv4(const float* __restrict__ sino,
                                                const float* __restrict__ wgt,
                                                uint4* __restrict__ dp4) {
    __shared__ float sw[4][DET];               // 3 KB
    const int d  = threadIdx.x;                // 0..191
    const int a  = blockIdx.x;                 // angle
    const int pc = blockIdx.y;                 // p-chunk (4 slices)

    #pragma unroll
    for (int j = 0; j < 4; ++j) {
        const int r = (4*pc + j) * NANG + a;   // sinogram row (p, a)
        sw[j][d] = sino[r*DET + d] * wgt[r*DET + d];
    }
    __syncthreads();

    unsigned pr[4];
    #pragma unroll
    for (int j = 0; j < 4; ++j) {
        const float* row = sw[j];
        auto grad = [&](int q) -> float {
            if (q == 0)       return row[1] - row[0];
            if (q >= DET-1)   return row[DET-1] - row[DET-2];
            return 0.5f * (row[q+1] - row[q-1]);
        };
        const float g0 = grad(d), g1 = grad(d + 1);
        pr[j] = pack2(g0, g1 - g0);
    }
    uint4 q; q.x = pr[0]; q.y = pr[1]; q.z = pr[2]; q.w = pr[3];
    dp4[((size_t)pc * SLICE) + a * DET + d] = q;   // coalesced 16B stores
}

// ---------------------------------------------------------------------------
// K2: 2D backprojection + cosine weighting — 4x16 WAVE-TILE mapping.
// r12 finding: K2 is bound by CACHELINE TOUCHES per wave-gather = the i0
// span of the wave's 64 lanes. Old mapping (wave = 64 consecutive u in one
// row): span = 63|cos| ~ 640B ~ 6 lines. New mapping (wave = 4 rows x 16
// cols tile): span = 15|cos|+3|sin| ~ 180B ~ 2.4 lines -> ~2.5x fewer
// touches in the dominant term. Same gathers, same per-pixel FDOT2 order
// -> bit-identical output; only lane->pixel assignment changes.
// Block = 512 thr = 4 rows x 128 cols (8 waves of 4x16); u+1 pair-partner
// at tile edges lands in the neighboring wave = SAME block -> LDS buf
// exchange unchanged (u=127 unused as before).
// grid (32 row-quads, 24 pc) = 768 blocks = 3/CU = 24 waves/CU.
// ---------------------------------------------------------------------------
__global__ __launch_bounds__(512) void k_bp2d_t4(const uint4* __restrict__ dp4,
                                                 unsigned* __restrict__ wq_dw,
                                                 uint2* __restrict__ tbl) {
    __shared__ float sc[NANG], ss[NANG];
    __shared__ float sc3[4], ss3[4];
    __shared__ float buf[4][4][129];           // [p-j][row][u], +1 pad
    const int tid  = threadIdx.x;              // 0..511
    const int w    = tid >> 6;                 // wave 0..7
    const int ln   = tid & 63;
    const int vloc = ln >> 4;                  // 0..3 (tile row)
    const int u    = (w << 4) | (ln & 15);     // 0..127
    const int v    = (blockIdx.x << 2) + vloc; // 0..127
    const int pix  = (v << 7) + u;
    const int pc   = blockIdx.y;               // p-chunk
    const int p0   = pc << 2;

    if (tid < NANG) {
        float s_, c_;
        sincosf((float)tid * (float)(3.14159265358979323846 / 96.0), &s_, &c_);
        sc[tid] = c_; ss[tid] = s_;
    }
    if (tid < 4) {
        float s_, c_;
        sincosf((float)(p0 + tid) * (float)(2.0 * 3.14159265358979323846 / 96.0), &s_, &c_);
        sc3[tid] = c_; ss3[tid] = s_;
    }

    const float fx = (float)u - 63.5f;
    const float fy = (float)v - 63.5f;

    float acc[4];
    #pragma unroll
    for (int j = 0; j < 4; ++j) acc[j] = 0.0f;

    __syncthreads();   // trig ready

    const uint4* bq = dp4 + (size_t)pc * SLICE;

    struct G { uint4 q; unsigned wv; };

    auto TRIG = [&](int a) -> float2 {
        return make_float2(sc[a], ss[a]);
    };
    auto ISSUE = [&](G& S, float2 T, int a) {
        const float pos = fmaf(T.x, fx, fmaf(T.y, fy, 95.5f));
        const int   i0  = (int)pos;            // pos in [5,186]
        const float f   = ffract(pos);
        S.wv = pack2(1.0f, f);
        S.q  = bq[a * DET + i0];               // ONE dwordx4 gather, tile-span
    };
    auto MATH = [&](const G& S) {
        const h2 wv = as_h2(S.wv);
        acc[0] = FDOT2(as_h2(S.q.x), wv, acc[0]);
        acc[1] = FDOT2(as_h2(S.q.y), wv, acc[1]);
        acc[2] = FDOT2(as_h2(S.q.z), wv, acc[2]);
        acc[3] = FDOT2(as_h2(S.q.w), wv, acc[3]);
    };

    G ga, gb;
    float2 Ta = TRIG(0);
    float2 Tb = TRIG(1);
    ISSUE(ga, Ta, 0);
    for (int a = 0; a < 94; a += 2) {
        Ta = TRIG(a + 2);           // 2-ahead trig prefetch
        ISSUE(gb, Tb, a + 1);       // 1-ahead gather issue
        MATH(ga);                   // consume gathers issued last half-iter
        Tb = TRIG(a + 3);           // max index 95 — no overrun
        ISSUE(ga, Ta, a + 2);
        MATH(gb);
    }
    ISSUE(gb, Tb, 95);
    MATH(ga);                       // angle 94
    MATH(gb);                       // angle 95

    const float wgt3 = 1000.0f * rsqrtf(1000000.0f + fx*fx + fy*fy);
    #pragma unroll
    for (int j = 0; j < 4; ++j) {
        acc[j] *= wgt3;
        buf[j][vloc][u] = acc[j];
    }
    __syncthreads();

    #pragma unroll
    for (int j = 0; j < 4; ++j) {
        const float v0 = acc[j];
        const float v1 = (u < 127) ? buf[j][vloc][u + 1] : 0.0f;  // u=127 unused
        const unsigned pr = pack2(v0, v1 - v0);
        unsigned* sq = wq_dw + (p0 + j) * (WQROWS * 128 * 4);
        #pragma unroll
        for (int k = 0; k < 4; ++k) {
            const int vb = v - k;
            if (vb >= WQROW0 && vb < WQROW0 + WQROWS)
                sq[(((vb - WQROW0) << 7) + u) << 2 | k] = pr;
        }
        // K3 prologue table entry for (p0+j, pix)
        const float cb3  = sc3[j], sb3 = ss3[j];
        const float t3   = fmaf(fx, cb3,  fy * sb3);
        const float sd3  = fmaf(fy, cb3, -fx * sb3);
        const float invr = frcp(500.0f + t3);
        const float pu   = fmaf(KPROJ * sd3, invr, 63.5f);
        const int   iu0  = (int)pu;              // [11,116]
        const float fu   = ffract(pu);
        float w2 = 1000.0f * invr; w2 *= w2;
        const float Kz   = KPROJ * invr;         // > 0
        const unsigned kzi = (__builtin_bit_cast(unsigned, Kz) & ~127u) | (unsigned)iu0;
        uint2 e; e.x = pack2(w2, fu * w2); e.y = kzi;
        tbl[(p0 + j) * NPIX + pix] = e;
    }
}

// ---------------------------------------------------------------------------
// K3: 3D cone-beam backprojection + PReLU — r8 version VERBATIM (~89-91 us):
// 32-bit SADDR addressing + 1-beta-ahead quad issue + 2-ahead table
// prefetch. grid (64 y-pairs, 32 z-chunks) = 2048 blocks = 32 waves/CU.
// pu in [11,116], pv in [19,108] -> no masks.
// ---------------------------------------------------------------------------
struct QS {
    uint4    q0, q1;           // quad rows ivA..ivA+3 for z-pairs 0,1
    unsigned wuw;              // (w2, fu*w2) packed fp16
    float    fvA0, fvB0, fvA1, fvB1;
    int      d0, d1;           // ivB - ivA (0 or 1)
};

__global__ __launch_bounds__(256, 8) void k_bp3d_t2(const unsigned char* __restrict__ wq,
                                                    const unsigned char* __restrict__ tbl8,
                                                    const float* __restrict__ prelu,
                                                    float* __restrict__ out) {
    const int tid = threadIdx.x;
    const int x   = tid & 127;
    const int y   = (blockIdx.x << 1) | (tid >> 7);
    const int z0  = blockIdx.y << 2;
    const int pix = (y << 7) + x;

    const float zlo = (float)z0 - 63.5f;

    float acc[4];
    #pragma unroll
    for (int j = 0; j < 4; ++j) acc[j] = 0.0f;

    const unsigned pixoff = ((unsigned)pix) << 3;      // tbl byte offset

    auto TLOAD = [&](int b) -> uint2 {
        return *(const uint2*)(tbl8 + (pixoff + (unsigned)b * (NPIX * 8u)));
    };

    auto ISSUE = [&](QS& S, uint2 T, int b) {
        S.wuw = T.x;
        const int   iu0 = (int)(T.y & 127u);
        const float Kz  = __builtin_bit_cast(float, T.y & ~127u);
        const unsigned sbase = (unsigned)b * (unsigned)WQSLICEB
                             + (unsigned)(iu0 << 4) - (unsigned)(WQROW0 << 11);

        const float pvA0 = fmaf(Kz, zlo, 63.5f);
        const float pvB0 = pvA0 + Kz;
        const int   ivA0 = (int)pvA0;            // [19,108]
        S.d0   = (int)pvB0 - ivA0;               // 0 or 1
        S.fvA0 = ffract(pvA0);
        S.fvB0 = ffract(pvB0);
        S.q0   = *(const uint4*)(wq + (sbase + ((unsigned)ivA0 << 11)));

        const float pvA1 = fmaf(Kz, zlo + 2.0f, 63.5f);
        const float pvB1 = pvA1 + Kz;
        const int   ivA1 = (int)pvA1;
        S.d1   = (int)pvB1 - ivA1;
        S.fvA1 = ffract(pvA1);
        S.fvB1 = ffract(pvB1);
        S.q1   = *(const uint4*)(wq + (sbase + ((unsigned)ivA1 << 11)));
    };

    auto MATH = [&](const QS& S) {
        const h2 wuw = as_h2(S.wuw);
        {
            const float tA = FDOT2(as_h2(S.q0.x), wuw, 0.0f);
            const float bA = FDOT2(as_h2(S.q0.y), wuw, 0.0f);
            acc[0] += fmaf(S.fvA0, bA - tA, tA);
            const unsigned tBv = S.d0 ? S.q0.y : S.q0.x;
            const unsigned bBv = S.d0 ? S.q0.z : S.q0.y;
            const float tB = FDOT2(as_h2(tBv), wuw, 0.0f);
            const float bB = FDOT2(as_h2(bBv), wuw, 0.0f);
            acc[1] += fmaf(S.fvB0, bB - tB, tB);
        }
        {
            const float tA = FDOT2(as_h2(S.q1.x), wuw, 0.0f);
            const float bA = FDOT2(as_h2(S.q1.y), wuw, 0.0f);
            acc[2] += fmaf(S.fvA1, bA - tA, tA);
            const unsigned tBv = S.d1 ? S.q1.y : S.q1.x;
            const unsigned bBv = S.d1 ? S.q1.z : S.q1.y;
            const float tB = FDOT2(as_h2(tBv), wuw, 0.0f);
            const float bB = FDOT2(as_h2(bBv), wuw, 0.0f);
            acc[3] += fmaf(S.fvB1, bB - tB, tB);
        }
    };

    QS qa, qb;
    uint2 Ta = TLOAD(0);
    uint2 Tb = TLOAD(1);
    ISSUE(qa, Ta, 0);
    for (int b = 0; b < 94; b += 2) {
        Ta = TLOAD(b + 2);          // 2-ahead table prefetch
        ISSUE(qb, Tb, b + 1);       // 1-ahead quad issue
        MATH(qa);                   // consume quads issued last half-iter
        Tb = TLOAD(b + 3);          // max index 95 — no overrun
        ISSUE(qa, Ta, b + 2);
        MATH(qb);
    }
    ISSUE(qb, Tb, 95);
    MATH(qa);                       // beta 94
    MATH(qb);                       // beta 95

    const float a = prelu[0];
    #pragma unroll
    for (int j = 0; j < 4; ++j) {
        const float v = acc[j];
        out[((z0 + j) << 14) + (y << 7) + x] = (v >= 0.0f) ? v : a * v;
    }
}

// ---------------------------------------------------------------------------
extern "C" void kernel_launch(void* const* d_in, const int* in_sizes, int n_in,
                              void* d_out, int out_size, void* d_ws, size_t ws_size,
                              hipStream_t stream) {
    const float* sino  = (const float*)d_in[0];   // (1,1,96,96,192)
    const float* wgt   = (const float*)d_in[1];   // (1,96,96,192)
    const float* prelu = (const float*)d_in[2];   // (1,)
    float* out = (float*)d_out;                   // 128^3 floats

    unsigned char* wsb = (unsigned char*)d_ws;
    unsigned* wq_dw  = (unsigned*)wsb;                                   // 18.87 MB quads (rows 16..111)
    uint2*    tbl    = (uint2*)(wsb + (size_t)NPROJ * WQSLICEB);         // 12.58 MB table
    uint4*    dp4    = (uint4*)(wsb + (size_t)NPROJ * WQSLICEB
                                     + (size_t)NPROJ * NPIX * 8);        // 7.08 MB p4-interleaved pairs

    k_deriv4 <<<dim3(NANG, NPROJ/4), dim3(192), 0, stream>>>(sino, wgt, dp4);   // 2304 blocks
    k_bp2d_t4<<<dim3(32, 24),        dim3(512), 0, stream>>>(dp4, wq_dw, tbl);  // 768 blocks x 512 thr
    k_bp3d_t2<<<dim3(64, 32),        dim3(256), 0, stream>>>((const unsigned char*)wq_dw,
                                                             (const unsigned char*)tbl, prelu, out);
}